// Round 9
// baseline (253.908 us; speedup 1.0000x reference)
//
#include <hip/hip_runtime.h>

typedef _Float16 f16;
typedef __attribute__((ext_vector_type(8))) _Float16 half8;
typedef __attribute__((ext_vector_type(4))) _Float16 half4;
typedef __attribute__((ext_vector_type(4))) float f32x4;

#define LDS_AS __attribute__((address_space(3)))
#define GLB_AS __attribute__((address_space(1)))

__device__ __forceinline__ void load16_lds(const f16* g, f16* l) {
    __builtin_amdgcn_global_load_lds((GLB_AS void*)(g), (LDS_AS void*)(l), 16, 0, 0);
}

#define WAIT8_BARRIER()  asm volatile("s_waitcnt vmcnt(8)\n\ts_barrier" ::: "memory")
#define WAIT4_BARRIER()  asm volatile("s_waitcnt vmcnt(4)\n\ts_barrier" ::: "memory")
#define WAIT0_BARRIER()  asm volatile("s_waitcnt vmcnt(0)\n\ts_barrier" ::: "memory")
// end-of-iteration barrier: lgkmcnt(0) pins this wave's ds_reads before the
// barrier so no wave can DMA into a buffer still being read (MFMA-sink race).
#define ENDBAR()         asm volatile("s_waitcnt lgkmcnt(0)\n\ts_barrier" ::: "memory")

// ---------------------------------------------------------------------------
// GEMM1: h_t[2048][11520] = W1t[2048][512] @ xh[11520][512]^T + b1(row), f16
// 3-stage pipelined K-loop (prefetch dist 2, vmcnt(8/4/0)); XCD swizzle.
// ---------------------------------------------------------------------------
__global__ __launch_bounds__(256, 3) void gemm1(
    const f16* __restrict__ A, const f16* __restrict__ Bt,
    const float* __restrict__ bias, f16* __restrict__ C)
{
    const int id  = blockIdx.x;
    const int xcd = id & 7;
    const int r   = id >> 3;
    const int mt  = r & 15;
    const int nt  = xcd + 8 * (r >> 4);
    if (nt >= 90) return;
    const int m0 = mt * 128, n0 = nt * 128;
    const int K = 512, ldc = 11520;

    __shared__ f16 smem[24576];        // 48 KB: 3 stages x (A 4096 | B 4096)
    const int tid  = threadIdx.x;
    const int wave = tid >> 6;
    const int lane = tid & 63;

    const int s1 = tid + 256;
    const f16* gA0 = A  + (m0 + (tid >> 2)) * K + (tid & 3) * 8;
    const f16* gA1 = A  + (m0 + (s1 >> 2)) * K + (s1 & 3) * 8;
    const f16* gB0 = Bt + (n0 + (tid >> 2)) * K + (tid & 3) * 8;
    const f16* gB1 = Bt + (n0 + (s1 >> 2)) * K + (s1 & 3) * 8;

    const int wm = (wave >> 1) * 64;
    const int wn = (wave & 1) * 64;
    const int lr = lane & 15;
    const int k8 = (lane >> 4) * 8;

    f32x4 acc[4][4];
#pragma unroll
    for (int i = 0; i < 4; ++i)
#pragma unroll
        for (int j = 0; j < 4; ++j) acc[i][j] = f32x4{0.f, 0.f, 0.f, 0.f};

#define G1_ISSUE(st, k0) do { \
    f16* sb_ = &smem[(st) * 8192]; \
    load16_lds(gA0 + (k0), sb_ + wave * 512); \
    load16_lds(gA1 + (k0), sb_ + 2048 + wave * 512); \
    load16_lds(gB0 + (k0), sb_ + 4096 + wave * 512); \
    load16_lds(gB1 + (k0), sb_ + 6144 + wave * 512); \
} while (0)

    G1_ISSUE(0, 0);
    G1_ISSUE(1, 32);
    const int NS = 16;                 // 512 / 32
    int cur = 0;
    for (int s = 0; s < NS; ++s) {
        if (s + 2 < NS) {
            int pre = cur + 2; if (pre >= 3) pre -= 3;
            G1_ISSUE(pre, (s + 2) * 32);
        }
        const int rem = NS - 1 - s;
        if (rem >= 2)      WAIT8_BARRIER();
        else if (rem == 1) WAIT4_BARRIER();
        else               WAIT0_BARRIER();
        const f16* sa = &smem[cur * 8192];
        half8 af[4], bf[4];
#pragma unroll
        for (int i = 0; i < 4; ++i)
            af[i] = *(const half8*)&sa[(wm + i * 16 + lr) * 32 + k8];
#pragma unroll
        for (int j = 0; j < 4; ++j)
            bf[j] = *(const half8*)&sa[4096 + (wn + j * 16 + lr) * 32 + k8];
#pragma unroll
        for (int i = 0; i < 4; ++i)
#pragma unroll
            for (int j = 0; j < 4; ++j)
                acc[i][j] = __builtin_amdgcn_mfma_f32_16x16x32_f16(
                    af[i], bf[j], acc[i][j], 0, 0, 0);
        ENDBAR();
        ++cur; if (cur >= 3) cur = 0;
    }

#pragma unroll
    for (int i = 0; i < 4; ++i) {
#pragma unroll
        for (int rr = 0; rr < 4; ++rr) {
            const int row = m0 + wm + i * 16 + (lane >> 4) * 4 + rr;
            const float bvr = (row < 1960) ? bias[row] : 0.f;
#pragma unroll
            for (int j = 0; j < 4; ++j) {
                const int col = n0 + wn + j * 16 + lr;
                C[row * ldc + col] = (f16)(acc[i][j][rr] + bvr);
            }
        }
    }
}

// ---------------------------------------------------------------------------
// GEMM2: out[11520][512] = g16[11520][2048] @ W2t[512][2048]^T + b2(col), f32
// 128x128 tile, 3-stage pipelined LDS (48 KB), vmcnt(8/4/0), XCD swizzle.
// (R8-passing version, unchanged.)
// ---------------------------------------------------------------------------
__global__ __launch_bounds__(256, 2) void gemm2(
    const f16* __restrict__ A, const f16* __restrict__ Bt,
    const float* __restrict__ bias, float* __restrict__ Cout)
{
    const int id  = blockIdx.x;
    const int xcd = id & 7;
    const int j2  = id >> 3;
    const int nt  = j2 & 3;
    const int mt  = (j2 >> 2) * 8 + xcd;
    if (mt >= 90) return;
    const int m0 = mt * 128, n0 = nt * 128;

    __shared__ f16 smem[24576];        // 48 KB: 3 stages x (A 4096 | B 4096)
    const int tid  = threadIdx.x;
    const int wave = tid >> 6;
    const int lane = tid & 63;

    const int s1 = tid + 256;
    const f16* gA0 = A  + (m0 + (tid >> 2)) * 2048 + (tid & 3) * 8;
    const f16* gA1 = A  + (m0 + (s1 >> 2)) * 2048 + (s1 & 3) * 8;
    const f16* gB0 = Bt + (n0 + (tid >> 2)) * 2048 + (tid & 3) * 8;
    const f16* gB1 = Bt + (n0 + (s1 >> 2)) * 2048 + (s1 & 3) * 8;

    const int wm = (wave >> 1) * 64;
    const int wn = (wave & 1) * 64;
    const int lr = lane & 15;
    const int k8 = (lane >> 4) * 8;

    f32x4 acc[4][4];
#pragma unroll
    for (int i = 0; i < 4; ++i)
#pragma unroll
        for (int j = 0; j < 4; ++j) acc[i][j] = f32x4{0.f, 0.f, 0.f, 0.f};

#define G2_ISSUE(st, k0) do { \
    f16* sb_ = &smem[(st) * 8192]; \
    load16_lds(gA0 + (k0), sb_ + wave * 512); \
    load16_lds(gA1 + (k0), sb_ + 2048 + wave * 512); \
    load16_lds(gB0 + (k0), sb_ + 4096 + wave * 512); \
    load16_lds(gB1 + (k0), sb_ + 6144 + wave * 512); \
} while (0)

    G2_ISSUE(0, 0);
    G2_ISSUE(1, 32);
    const int NS = 64;                 // 2048 / 32
    int cur = 0;
    for (int s = 0; s < NS; ++s) {
        if (s + 2 < NS) {
            int pre = cur + 2; if (pre >= 3) pre -= 3;
            G2_ISSUE(pre, (s + 2) * 32);
        }
        const int rem = NS - 1 - s;
        if (rem >= 2)      WAIT8_BARRIER();
        else if (rem == 1) WAIT4_BARRIER();
        else               WAIT0_BARRIER();
        const f16* sa = &smem[cur * 8192];
        half8 af[4], bf[4];
#pragma unroll
        for (int i = 0; i < 4; ++i)
            af[i] = *(const half8*)&sa[(wm + i * 16 + lr) * 32 + k8];
#pragma unroll
        for (int j = 0; j < 4; ++j)
            bf[j] = *(const half8*)&sa[4096 + (wn + j * 16 + lr) * 32 + k8];
#pragma unroll
        for (int i = 0; i < 4; ++i)
#pragma unroll
            for (int j = 0; j < 4; ++j)
                acc[i][j] = __builtin_amdgcn_mfma_f32_16x16x32_f16(
                    af[i], bf[j], acc[i][j], 0, 0, 0);
        ENDBAR();
        ++cur; if (cur >= 3) cur = 0;
    }

#pragma unroll
    for (int j = 0; j < 4; ++j) {
        const int col = n0 + wn + j * 16 + lr;
        const float bv = bias[col];
#pragma unroll
        for (int i = 0; i < 4; ++i) {
            const int rbase = m0 + wm + i * 16 + (lane >> 4) * 4;
#pragma unroll
            for (int rr = 0; rr < 4; ++rr)
                Cout[(rbase + rr) * 512 + col] = acc[i][j][rr] + bv;
        }
    }
}

// ---------------------------------------------------------------------------
// fold + normalize + GELU + unfold, fused. One block per bc = bp*40+cch.
// Phase 1: compute 66x114 channel image (zero ring) into LDS from h_t.
// Phase 2: unfold from LDS -> g16[token][2048]; cch>=36 also zeros tail cols.
// ---------------------------------------------------------------------------
__global__ __launch_bounds__(256) void fold_unfold(
    const f16* __restrict__ h_t, f16* __restrict__ g16)
{
    __shared__ f16 ch[7524];
    const int bc = blockIdx.x;        // 0..639
    const int bp = bc / 40, cch = bc % 40;

    for (int flat = threadIdx.x; flat < 7524; flat += 256) {
        const int r = flat / 114, c = flat - r * 114;
        float outv = 0.f;
        if (r >= 3 && r < 63 && c >= 3 && c < 111) {
            const int qr = r / 3, rm = r % 3;
            const int qc = c / 3, cm = c % 3;
            int kis[3], ohs[3], nr = 0;
            int kjs[3], ows[3], nc = 0;
#pragma unroll
            for (int t = 0; t < 3; ++t) {
                const int ki = rm + 3 * t, oh = qr - t;
                if (ki < 7 && oh >= 0 && oh < 20) { kis[nr] = ki; ohs[nr] = oh; ++nr; }
                const int kj = cm + 3 * t, ow = qc - t;
                if (kj < 7 && ow >= 0 && ow < 36) { kjs[nc] = kj; ows[nc] = ow; ++nc; }
            }
            float sum = 0.f;
            for (int a = 0; a < nr; ++a)
                for (int b = 0; b < nc; ++b) {
                    const int n = cch * 49 + kis[a] * 7 + kjs[b];
                    const int token = bp * 720 + ohs[a] * 36 + ows[b];
                    sum += (float)h_t[n * 11520 + token];
                }
            const float xv = sum / (float)(nr * nc);
            outv = 0.5f * xv * (1.f + erff(xv * 0.70710678118654752f));
        }
        ch[flat] = (f16)outv;
    }
    __syncthreads();

    const int tokbase = bp * 720;
    const int colbase = cch * 49;
    for (int flat = threadIdx.x; flat < 35280; flat += 256) {
        const int l = flat / 49, k = flat - l * 49;
        const int oh = l / 36, ow = l - oh * 36;
        const int ki = k / 7,  kj = k - ki * 7;
        g16[(tokbase + l) * 2048 + colbase + k] =
            ch[(oh * 3 + ki) * 114 + ow * 3 + kj];
    }
    if (cch >= 36) {
        const int cb = 1960 + (cch - 36) * 22;   // 4 blocks x 22 cols = 88
        for (int flat = threadIdx.x; flat < 720 * 22; flat += 256) {
            const int l = flat / 22, k = flat - l * 22;
            g16[(tokbase + l) * 2048 + cb + k] = (f16)0.f;
        }
    }
}

// ---------------------------------------------------------------------------
// prep: fuses x->f16 convert + both weight transposes (one dispatch).
// blocks [0,5760): cvt; [5760,6784): W1 -> W1t; [6784,7808): W2 -> W2t
// ---------------------------------------------------------------------------
__global__ __launch_bounds__(256) void prep(
    const float* __restrict__ x, f16* __restrict__ xh,
    const float* __restrict__ W1, f16* __restrict__ W1t,
    const float* __restrict__ W2, f16* __restrict__ W2t)
{
    __shared__ float tile[32][33];
    const int b = blockIdx.x, t = threadIdx.x;
    if (b < 5760) {
        const int i = b * 256 + t;     // < 1474560 float4s
        const float4 v = ((const float4*)x)[i];
        half4 o;
        o[0] = (f16)v.x; o[1] = (f16)v.y; o[2] = (f16)v.z; o[3] = (f16)v.w;
        ((half4*)xh)[i] = o;
        return;
    }
    const float* src; f16* dst; int R, C, Rp, Cp, bx, by;
    if (b < 6784) {
        const int local = b - 5760;    // grid (16,64)
        bx = local & 15; by = local >> 4;
        src = W1; dst = W1t; R = 512; C = 1960; Rp = 512; Cp = 2048;
    } else {
        const int local = b - 6784;    // grid (64,16)
        bx = local & 63; by = local >> 6;
        src = W2; dst = W2t; R = 1960; C = 512; Rp = 2048; Cp = 512;
    }
    const int r0 = bx * 32, c0 = by * 32;
    const int tx = t & 31, ty = t >> 5;
#pragma unroll
    for (int i = 0; i < 32; i += 8) {
        const int r = r0 + ty + i, c = c0 + tx;
        tile[ty + i][tx] = (r < R && c < C) ? src[r * C + c] : 0.f;
    }
    __syncthreads();
#pragma unroll
    for (int i = 0; i < 32; i += 8) {
        const int c = c0 + ty + i, r = r0 + tx;
        if (c < Cp && r < Rp) dst[c * Rp + r] = (f16)tile[tx][ty + i];
    }
}

// ---------------------------------------------------------------------------
extern "C" void kernel_launch(void* const* d_in, const int* in_sizes, int n_in,
                              void* d_out, int out_size, void* d_ws, size_t ws_size,
                              hipStream_t stream)
{
    const float* x  = (const float*)d_in[0];
    const float* W1 = (const float*)d_in[1];
    const float* b1 = (const float*)d_in[2];
    const float* W2 = (const float*)d_in[3];
    const float* b2 = (const float*)d_in[4];

    char* ws = (char*)d_ws;
    f16* xh   = (f16*)(ws);                                       // 11,796,480 B
    f16* W1t  = (f16*)(ws + 11796480);                            //  2,097,152 B
    f16* W2t  = (f16*)(ws + 11796480 + 2097152);                  //  2,097,152 B
    f16* h_t  = (f16*)(ws + 11796480 + 2 * 2097152);              // 47,185,920 B
    f16* g16  = (f16*)(ws + 11796480 + 2 * 2097152 + 47185920);   // 47,185,920 B

    // fused convert + transposes
    prep<<<dim3(7808), dim3(256), 0, stream>>>(x, xh, W1, W1t, W2, W2t);
    // GEMM1 (3-stage pipelined): h_t = W1t @ xh^T + b1(row)
    gemm1<<<dim3(1536), dim3(256), 0, stream>>>(W1t, xh, b1, h_t);
    // fused fold + normalize + GELU + unfold: h_t -> g16[token][2048]
    fold_unfold<<<dim3(640), dim3(256), 0, stream>>>(h_t, g16);
    // GEMM2 (3-stage pipeline, XCD-swizzled): out = g16 @ W2t^T + b2
    gemm2<<<dim3(384), dim3(256), 0, stream>>>(g16, W2t, b2, (float*)d_out);
}

// Round 10
// 224.333 us; speedup vs baseline: 1.1318x; 1.1318x over previous
//
#include <hip/hip_runtime.h>

typedef _Float16 f16;
typedef __attribute__((ext_vector_type(8))) _Float16 half8;
typedef __attribute__((ext_vector_type(4))) _Float16 half4;
typedef __attribute__((ext_vector_type(4))) float f32x4;

#define LDS_AS __attribute__((address_space(3)))
#define GLB_AS __attribute__((address_space(1)))

__device__ __forceinline__ void load16_lds(const f16* g, f16* l) {
    __builtin_amdgcn_global_load_lds((GLB_AS void*)(g), (LDS_AS void*)(l), 16, 0, 0);
}

#define WAIT8_BARRIER()  asm volatile("s_waitcnt vmcnt(8)\n\ts_barrier" ::: "memory")
#define WAIT4_BARRIER()  asm volatile("s_waitcnt vmcnt(4)\n\ts_barrier" ::: "memory")
#define WAIT0_BARRIER()  asm volatile("s_waitcnt vmcnt(0)\n\ts_barrier" ::: "memory")
// end-of-iteration barrier: lgkmcnt(0) pins this wave's ds_reads before the
// barrier so no wave can DMA into a buffer still being read (MFMA-sink race).
#define ENDBAR()         asm volatile("s_waitcnt lgkmcnt(0)\n\ts_barrier" ::: "memory")

// ---------------------------------------------------------------------------
// GEMM1: h_t[2048][11520] = W1t[2048][512] @ xh[11520][512]^T + b1(row), f16
// 3-stage pipelined K-loop (prefetch dist 2, vmcnt(8/4/0)); XCD swizzle.
// ---------------------------------------------------------------------------
__global__ __launch_bounds__(256, 3) void gemm1(
    const f16* __restrict__ A, const f16* __restrict__ Bt,
    const float* __restrict__ bias, f16* __restrict__ C)
{
    const int id  = blockIdx.x;
    const int xcd = id & 7;
    const int r   = id >> 3;
    const int mt  = r & 15;
    const int nt  = xcd + 8 * (r >> 4);
    if (nt >= 90) return;
    const int m0 = mt * 128, n0 = nt * 128;
    const int K = 512, ldc = 11520;

    __shared__ f16 smem[24576];        // 48 KB: 3 stages x (A 4096 | B 4096)
    const int tid  = threadIdx.x;
    const int wave = tid >> 6;
    const int lane = tid & 63;

    const int s1 = tid + 256;
    const f16* gA0 = A  + (m0 + (tid >> 2)) * K + (tid & 3) * 8;
    const f16* gA1 = A  + (m0 + (s1 >> 2)) * K + (s1 & 3) * 8;
    const f16* gB0 = Bt + (n0 + (tid >> 2)) * K + (tid & 3) * 8;
    const f16* gB1 = Bt + (n0 + (s1 >> 2)) * K + (s1 & 3) * 8;

    const int wm = (wave >> 1) * 64;
    const int wn = (wave & 1) * 64;
    const int lr = lane & 15;
    const int k8 = (lane >> 4) * 8;

    f32x4 acc[4][4];
#pragma unroll
    for (int i = 0; i < 4; ++i)
#pragma unroll
        for (int j = 0; j < 4; ++j) acc[i][j] = f32x4{0.f, 0.f, 0.f, 0.f};

#define G1_ISSUE(st, k0) do { \
    f16* sb_ = &smem[(st) * 8192]; \
    load16_lds(gA0 + (k0), sb_ + wave * 512); \
    load16_lds(gA1 + (k0), sb_ + 2048 + wave * 512); \
    load16_lds(gB0 + (k0), sb_ + 4096 + wave * 512); \
    load16_lds(gB1 + (k0), sb_ + 6144 + wave * 512); \
} while (0)

    G1_ISSUE(0, 0);
    G1_ISSUE(1, 32);
    const int NS = 16;                 // 512 / 32
    int cur = 0;
    for (int s = 0; s < NS; ++s) {
        if (s + 2 < NS) {
            int pre = cur + 2; if (pre >= 3) pre -= 3;
            G1_ISSUE(pre, (s + 2) * 32);
        }
        const int rem = NS - 1 - s;
        if (rem >= 2)      WAIT8_BARRIER();
        else if (rem == 1) WAIT4_BARRIER();
        else               WAIT0_BARRIER();
        const f16* sa = &smem[cur * 8192];
        half8 af[4], bf[4];
#pragma unroll
        for (int i = 0; i < 4; ++i)
            af[i] = *(const half8*)&sa[(wm + i * 16 + lr) * 32 + k8];
#pragma unroll
        for (int j = 0; j < 4; ++j)
            bf[j] = *(const half8*)&sa[4096 + (wn + j * 16 + lr) * 32 + k8];
#pragma unroll
        for (int i = 0; i < 4; ++i)
#pragma unroll
            for (int j = 0; j < 4; ++j)
                acc[i][j] = __builtin_amdgcn_mfma_f32_16x16x32_f16(
                    af[i], bf[j], acc[i][j], 0, 0, 0);
        ENDBAR();
        ++cur; if (cur >= 3) cur = 0;
    }

#pragma unroll
    for (int i = 0; i < 4; ++i) {
#pragma unroll
        for (int rr = 0; rr < 4; ++rr) {
            const int row = m0 + wm + i * 16 + (lane >> 4) * 4 + rr;
            const float bvr = (row < 1960) ? bias[row] : 0.f;
#pragma unroll
            for (int j = 0; j < 4; ++j) {
                const int col = n0 + wn + j * 16 + lr;
                C[row * ldc + col] = (f16)(acc[i][j][rr] + bvr);
            }
        }
    }
}

// ---------------------------------------------------------------------------
// GEMM2: out[11520][512] = g16[11520][2048] @ W2t[512][2048]^T + b2(col), f32
// 128x128 tile, 3-stage pipelined LDS (48 KB), vmcnt(8/4/0), XCD swizzle.
// ---------------------------------------------------------------------------
__global__ __launch_bounds__(256, 2) void gemm2(
    const f16* __restrict__ A, const f16* __restrict__ Bt,
    const float* __restrict__ bias, float* __restrict__ Cout)
{
    const int id  = blockIdx.x;
    const int xcd = id & 7;
    const int j2  = id >> 3;
    const int nt  = j2 & 3;
    const int mt  = (j2 >> 2) * 8 + xcd;
    if (mt >= 90) return;
    const int m0 = mt * 128, n0 = nt * 128;

    __shared__ f16 smem[24576];        // 48 KB: 3 stages x (A 4096 | B 4096)
    const int tid  = threadIdx.x;
    const int wave = tid >> 6;
    const int lane = tid & 63;

    const int s1 = tid + 256;
    const f16* gA0 = A  + (m0 + (tid >> 2)) * 2048 + (tid & 3) * 8;
    const f16* gA1 = A  + (m0 + (s1 >> 2)) * 2048 + (s1 & 3) * 8;
    const f16* gB0 = Bt + (n0 + (tid >> 2)) * 2048 + (tid & 3) * 8;
    const f16* gB1 = Bt + (n0 + (s1 >> 2)) * 2048 + (s1 & 3) * 8;

    const int wm = (wave >> 1) * 64;
    const int wn = (wave & 1) * 64;
    const int lr = lane & 15;
    const int k8 = (lane >> 4) * 8;

    f32x4 acc[4][4];
#pragma unroll
    for (int i = 0; i < 4; ++i)
#pragma unroll
        for (int j = 0; j < 4; ++j) acc[i][j] = f32x4{0.f, 0.f, 0.f, 0.f};

#define G2_ISSUE(st, k0) do { \
    f16* sb_ = &smem[(st) * 8192]; \
    load16_lds(gA0 + (k0), sb_ + wave * 512); \
    load16_lds(gA1 + (k0), sb_ + 2048 + wave * 512); \
    load16_lds(gB0 + (k0), sb_ + 4096 + wave * 512); \
    load16_lds(gB1 + (k0), sb_ + 6144 + wave * 512); \
} while (0)

    G2_ISSUE(0, 0);
    G2_ISSUE(1, 32);
    const int NS = 64;                 // 2048 / 32
    int cur = 0;
    for (int s = 0; s < NS; ++s) {
        if (s + 2 < NS) {
            int pre = cur + 2; if (pre >= 3) pre -= 3;
            G2_ISSUE(pre, (s + 2) * 32);
        }
        const int rem = NS - 1 - s;
        if (rem >= 2)      WAIT8_BARRIER();
        else if (rem == 1) WAIT4_BARRIER();
        else               WAIT0_BARRIER();
        const f16* sa = &smem[cur * 8192];
        half8 af[4], bf[4];
#pragma unroll
        for (int i = 0; i < 4; ++i)
            af[i] = *(const half8*)&sa[(wm + i * 16 + lr) * 32 + k8];
#pragma unroll
        for (int j = 0; j < 4; ++j)
            bf[j] = *(const half8*)&sa[4096 + (wn + j * 16 + lr) * 32 + k8];
#pragma unroll
        for (int i = 0; i < 4; ++i)
#pragma unroll
            for (int j = 0; j < 4; ++j)
                acc[i][j] = __builtin_amdgcn_mfma_f32_16x16x32_f16(
                    af[i], bf[j], acc[i][j], 0, 0, 0);
        ENDBAR();
        ++cur; if (cur >= 3) cur = 0;
    }

#pragma unroll
    for (int j = 0; j < 4; ++j) {
        const int col = n0 + wn + j * 16 + lr;
        const float bv = bias[col];
#pragma unroll
        for (int i = 0; i < 4; ++i) {
            const int rbase = m0 + wm + i * 16 + (lane >> 4) * 4;
#pragma unroll
            for (int rr = 0; rr < 4; ++rr)
                Cout[(rbase + rr) * 512 + col] = acc[i][j][rr] + bv;
        }
    }
}

// ---------------------------------------------------------------------------
// fold + normalize + GELU + unfold, fused; gathers served from LDS.
// Block per bc = bp*40+cch. Two row-halves; each stages its 49x396 h_t band
// (38.8 KB, coalesced half4 loads) into LDS, folds from LDS into ch[], then
// one unfold phase writes g16. 512 threads, 53.9 KB LDS -> 2 blocks/CU.
// ---------------------------------------------------------------------------
__global__ __launch_bounds__(512, 2) void fold_unfold(
    const f16* __restrict__ h_t, f16* __restrict__ g16)
{
    __shared__ f16 ch[7524];           // 66x114 channel image
    __shared__ f16 stg[19404];         // 49 taps x 396 tokens (11 oh-rows)
    const int bc = blockIdx.x;         // 0..639
    const int bp = bc / 40, cch = bc % 40;
    const int tid = threadIdx.x;

#pragma unroll
    for (int h = 0; h < 2; ++h) {
        const int ohlo = h * 9;        // half0: oh 0..10, half1: oh 9..19
        // stage band: stg[n*396 + (oh-ohlo)*36 + ow]
        const int src0 = cch * 49 * 11520 + bp * 720 + ohlo * 36;
        for (int idx = tid; idx < 4851; idx += 512) {
            const int n = idx / 99, i = idx - n * 99;
            *(half4*)&stg[n * 396 + i * 4] =
                *(const half4*)&h_t[src0 + n * 11520 + i * 4];
        }
        __syncthreads();
        // fold rows [h*33, h*33+33)
        for (int flat = tid; flat < 3762; flat += 512) {
            const int r = h * 33 + flat / 114;
            const int c = flat - (flat / 114) * 114;
            float outv = 0.f;
            if (r >= 3 && r < 63 && c >= 3 && c < 111) {
                const int qr = r / 3, rm = r % 3;
                const int qc = c / 3, cm = c % 3;
                int kis[3], ohs[3], nr = 0;
                int kjs[3], ows[3], nc = 0;
#pragma unroll
                for (int t = 0; t < 3; ++t) {
                    const int ki = rm + 3 * t, oh = qr - t;
                    if (ki < 7 && oh >= 0 && oh < 20) { kis[nr] = ki; ohs[nr] = oh; ++nr; }
                    const int kj = cm + 3 * t, ow = qc - t;
                    if (kj < 7 && ow >= 0 && ow < 36) { kjs[nc] = kj; ows[nc] = ow; ++nc; }
                }
                float sum = 0.f;
                for (int a = 0; a < nr; ++a)
                    for (int b = 0; b < nc; ++b)
                        sum += (float)stg[(kis[a] * 7 + kjs[b]) * 396 +
                                          (ohs[a] - ohlo) * 36 + ows[b]];
                const float xv = sum / (float)(nr * nc);
                outv = 0.5f * xv * (1.f + erff(xv * 0.70710678118654752f));
            }
            ch[r * 114 + c] = (f16)outv;
        }
        __syncthreads();               // protects stg reuse + ch completion
    }

    // unfold: ch -> g16[token][2048]
    const int tokbase = bp * 720;
    const int colbase = cch * 49;
    for (int flat = tid; flat < 35280; flat += 512) {
        const int l = flat / 49, k = flat - l * 49;
        const int oh = l / 36, ow = l - oh * 36;
        const int ki = k / 7,  kj = k - ki * 7;
        g16[(tokbase + l) * 2048 + colbase + k] =
            ch[(oh * 3 + ki) * 114 + ow * 3 + kj];
    }
    if (cch >= 36) {
        const int cb = 1960 + (cch - 36) * 22;   // 4 blocks x 22 cols = 88
        for (int flat = tid; flat < 720 * 22; flat += 512) {
            const int l = flat / 22, k = flat - l * 22;
            g16[(tokbase + l) * 2048 + cb + k] = (f16)0.f;
        }
    }
}

// ---------------------------------------------------------------------------
// prep: fuses x->f16 convert + both weight transposes (one dispatch).
// blocks [0,5760): cvt; [5760,6784): W1 -> W1t; [6784,7808): W2 -> W2t
// ---------------------------------------------------------------------------
__global__ __launch_bounds__(256) void prep(
    const float* __restrict__ x, f16* __restrict__ xh,
    const float* __restrict__ W1, f16* __restrict__ W1t,
    const float* __restrict__ W2, f16* __restrict__ W2t)
{
    __shared__ float tile[32][33];
    const int b = blockIdx.x, t = threadIdx.x;
    if (b < 5760) {
        const int i = b * 256 + t;     // < 1474560 float4s
        const float4 v = ((const float4*)x)[i];
        half4 o;
        o[0] = (f16)v.x; o[1] = (f16)v.y; o[2] = (f16)v.z; o[3] = (f16)v.w;
        ((half4*)xh)[i] = o;
        return;
    }
    const float* src; f16* dst; int R, C, Rp, Cp, bx, by;
    if (b < 6784) {
        const int local = b - 5760;    // grid (16,64)
        bx = local & 15; by = local >> 4;
        src = W1; dst = W1t; R = 512; C = 1960; Rp = 512; Cp = 2048;
    } else {
        const int local = b - 6784;    // grid (64,16)
        bx = local & 63; by = local >> 6;
        src = W2; dst = W2t; R = 1960; C = 512; Rp = 2048; Cp = 512;
    }
    const int r0 = bx * 32, c0 = by * 32;
    const int tx = t & 31, ty = t >> 5;
#pragma unroll
    for (int i = 0; i < 32; i += 8) {
        const int r = r0 + ty + i, c = c0 + tx;
        tile[ty + i][tx] = (r < R && c < C) ? src[r * C + c] : 0.f;
    }
    __syncthreads();
#pragma unroll
    for (int i = 0; i < 32; i += 8) {
        const int c = c0 + ty + i, r = r0 + tx;
        if (c < Cp && r < Rp) dst[c * Rp + r] = (f16)tile[tx][ty + i];
    }
}

// ---------------------------------------------------------------------------
extern "C" void kernel_launch(void* const* d_in, const int* in_sizes, int n_in,
                              void* d_out, int out_size, void* d_ws, size_t ws_size,
                              hipStream_t stream)
{
    const float* x  = (const float*)d_in[0];
    const float* W1 = (const float*)d_in[1];
    const float* b1 = (const float*)d_in[2];
    const float* W2 = (const float*)d_in[3];
    const float* b2 = (const float*)d_in[4];

    char* ws = (char*)d_ws;
    f16* xh   = (f16*)(ws);                                       // 11,796,480 B
    f16* W1t  = (f16*)(ws + 11796480);                            //  2,097,152 B
    f16* W2t  = (f16*)(ws + 11796480 + 2097152);                  //  2,097,152 B
    f16* h_t  = (f16*)(ws + 11796480 + 2 * 2097152);              // 47,185,920 B
    f16* g16  = (f16*)(ws + 11796480 + 2 * 2097152 + 47185920);   // 47,185,920 B

    // fused convert + transposes
    prep<<<dim3(7808), dim3(256), 0, stream>>>(x, xh, W1, W1t, W2, W2t);
    // GEMM1 (3-stage pipelined): h_t = W1t @ xh^T + b1(row)
    gemm1<<<dim3(1536), dim3(256), 0, stream>>>(W1t, xh, b1, h_t);
    // fused fold + normalize + GELU + unfold (LDS-staged gathers)
    fold_unfold<<<dim3(640), dim3(512), 0, stream>>>(h_t, g16);
    // GEMM2 (3-stage pipeline, XCD-swizzled): out = g16 @ W2t^T + b2
    gemm2<<<dim3(384), dim3(256), 0, stream>>>(g16, W2t, b2, (float*)d_out);
}

// Round 12
// 195.694 us; speedup vs baseline: 1.2975x; 1.1463x over previous
//
#include <hip/hip_runtime.h>

typedef _Float16 f16;
typedef __attribute__((ext_vector_type(8))) _Float16 half8;
typedef __attribute__((ext_vector_type(4))) _Float16 half4;
typedef __attribute__((ext_vector_type(4))) float f32x4;

#define LDS_AS __attribute__((address_space(3)))
#define GLB_AS __attribute__((address_space(1)))

__device__ __forceinline__ void load16_lds(const f16* g, f16* l) {
    __builtin_amdgcn_global_load_lds((GLB_AS void*)(g), (LDS_AS void*)(l), 16, 0, 0);
}

#define WAIT8_BARRIER()  asm volatile("s_waitcnt vmcnt(8)\n\ts_barrier" ::: "memory")
#define WAIT4_BARRIER()  asm volatile("s_waitcnt vmcnt(4)\n\ts_barrier" ::: "memory")
#define WAIT0_BARRIER()  asm volatile("s_waitcnt vmcnt(0)\n\ts_barrier" ::: "memory")
// end-of-iteration barrier: lgkmcnt(0) pins this wave's ds_reads before the
// barrier so no wave can DMA into a buffer still being read (MFMA-sink race).
#define ENDBAR()         asm volatile("s_waitcnt lgkmcnt(0)\n\ts_barrier" ::: "memory")

// ---------------------------------------------------------------------------
// GEMM1: h_t[2048][11520] = W1t[2048][512] @ xh[11520][512]^T + b1(row), f16
// 3-stage pipelined K-loop (prefetch dist 2, vmcnt(8/4/0)); XCD swizzle.
// ---------------------------------------------------------------------------
__global__ __launch_bounds__(256, 3) void gemm1(
    const f16* __restrict__ A, const f16* __restrict__ Bt,
    const float* __restrict__ bias, f16* __restrict__ C)
{
    const int id  = blockIdx.x;
    const int xcd = id & 7;
    const int r   = id >> 3;
    const int mt  = r & 15;
    const int nt  = xcd + 8 * (r >> 4);
    if (nt >= 90) return;
    const int m0 = mt * 128, n0 = nt * 128;
    const int K = 512, ldc = 11520;

    __shared__ f16 smem[24576];        // 48 KB: 3 stages x (A 4096 | B 4096)
    const int tid  = threadIdx.x;
    const int wave = tid >> 6;
    const int lane = tid & 63;

    const int s1 = tid + 256;
    const f16* gA0 = A  + (m0 + (tid >> 2)) * K + (tid & 3) * 8;
    const f16* gA1 = A  + (m0 + (s1 >> 2)) * K + (s1 & 3) * 8;
    const f16* gB0 = Bt + (n0 + (tid >> 2)) * K + (tid & 3) * 8;
    const f16* gB1 = Bt + (n0 + (s1 >> 2)) * K + (s1 & 3) * 8;

    const int wm = (wave >> 1) * 64;
    const int wn = (wave & 1) * 64;
    const int lr = lane & 15;
    const int k8 = (lane >> 4) * 8;

    f32x4 acc[4][4];
#pragma unroll
    for (int i = 0; i < 4; ++i)
#pragma unroll
        for (int j = 0; j < 4; ++j) acc[i][j] = f32x4{0.f, 0.f, 0.f, 0.f};

#define G1_ISSUE(st, k0) do { \
    f16* sb_ = &smem[(st) * 8192]; \
    load16_lds(gA0 + (k0), sb_ + wave * 512); \
    load16_lds(gA1 + (k0), sb_ + 2048 + wave * 512); \
    load16_lds(gB0 + (k0), sb_ + 4096 + wave * 512); \
    load16_lds(gB1 + (k0), sb_ + 6144 + wave * 512); \
} while (0)

    G1_ISSUE(0, 0);
    G1_ISSUE(1, 32);
    const int NS = 16;                 // 512 / 32
    int cur = 0;
    for (int s = 0; s < NS; ++s) {
        if (s + 2 < NS) {
            int pre = cur + 2; if (pre >= 3) pre -= 3;
            G1_ISSUE(pre, (s + 2) * 32);
        }
        const int rem = NS - 1 - s;
        if (rem >= 2)      WAIT8_BARRIER();
        else if (rem == 1) WAIT4_BARRIER();
        else               WAIT0_BARRIER();
        const f16* sa = &smem[cur * 8192];
        half8 af[4], bf[4];
#pragma unroll
        for (int i = 0; i < 4; ++i)
            af[i] = *(const half8*)&sa[(wm + i * 16 + lr) * 32 + k8];
#pragma unroll
        for (int j = 0; j < 4; ++j)
            bf[j] = *(const half8*)&sa[4096 + (wn + j * 16 + lr) * 32 + k8];
#pragma unroll
        for (int i = 0; i < 4; ++i)
#pragma unroll
            for (int j = 0; j < 4; ++j)
                acc[i][j] = __builtin_amdgcn_mfma_f32_16x16x32_f16(
                    af[i], bf[j], acc[i][j], 0, 0, 0);
        ENDBAR();
        ++cur; if (cur >= 3) cur = 0;
    }

#pragma unroll
    for (int i = 0; i < 4; ++i) {
#pragma unroll
        for (int rr = 0; rr < 4; ++rr) {
            const int row = m0 + wm + i * 16 + (lane >> 4) * 4 + rr;
            const float bvr = (row < 1960) ? bias[row] : 0.f;
#pragma unroll
            for (int j = 0; j < 4; ++j) {
                const int col = n0 + wn + j * 16 + lr;
                C[row * ldc + col] = (f16)(acc[i][j][rr] + bvr);
            }
        }
    }
}

// ---------------------------------------------------------------------------
// GEMM2: out[11520][512] = g16[11520][2048] @ W2t[512][2048]^T + b2(col), f32
// 128x128 tile, 3-stage pipelined LDS (48 KB), vmcnt(8/4/0), XCD swizzle.
// ---------------------------------------------------------------------------
__global__ __launch_bounds__(256, 2) void gemm2(
    const f16* __restrict__ A, const f16* __restrict__ Bt,
    const float* __restrict__ bias, float* __restrict__ Cout)
{
    const int id  = blockIdx.x;
    const int xcd = id & 7;
    const int j2  = id >> 3;
    const int nt  = j2 & 3;
    const int mt  = (j2 >> 2) * 8 + xcd;
    if (mt >= 90) return;
    const int m0 = mt * 128, n0 = nt * 128;

    __shared__ f16 smem[24576];        // 48 KB: 3 stages x (A 4096 | B 4096)
    const int tid  = threadIdx.x;
    const int wave = tid >> 6;
    const int lane = tid & 63;

    const int s1 = tid + 256;
    const f16* gA0 = A  + (m0 + (tid >> 2)) * 2048 + (tid & 3) * 8;
    const f16* gA1 = A  + (m0 + (s1 >> 2)) * 2048 + (s1 & 3) * 8;
    const f16* gB0 = Bt + (n0 + (tid >> 2)) * 2048 + (tid & 3) * 8;
    const f16* gB1 = Bt + (n0 + (s1 >> 2)) * 2048 + (s1 & 3) * 8;

    const int wm = (wave >> 1) * 64;
    const int wn = (wave & 1) * 64;
    const int lr = lane & 15;
    const int k8 = (lane >> 4) * 8;

    f32x4 acc[4][4];
#pragma unroll
    for (int i = 0; i < 4; ++i)
#pragma unroll
        for (int j = 0; j < 4; ++j) acc[i][j] = f32x4{0.f, 0.f, 0.f, 0.f};

#define G2_ISSUE(st, k0) do { \
    f16* sb_ = &smem[(st) * 8192]; \
    load16_lds(gA0 + (k0), sb_ + wave * 512); \
    load16_lds(gA1 + (k0), sb_ + 2048 + wave * 512); \
    load16_lds(gB0 + (k0), sb_ + 4096 + wave * 512); \
    load16_lds(gB1 + (k0), sb_ + 6144 + wave * 512); \
} while (0)

    G2_ISSUE(0, 0);
    G2_ISSUE(1, 32);
    const int NS = 64;                 // 2048 / 32
    int cur = 0;
    for (int s = 0; s < NS; ++s) {
        if (s + 2 < NS) {
            int pre = cur + 2; if (pre >= 3) pre -= 3;
            G2_ISSUE(pre, (s + 2) * 32);
        }
        const int rem = NS - 1 - s;
        if (rem >= 2)      WAIT8_BARRIER();
        else if (rem == 1) WAIT4_BARRIER();
        else               WAIT0_BARRIER();
        const f16* sa = &smem[cur * 8192];
        half8 af[4], bf[4];
#pragma unroll
        for (int i = 0; i < 4; ++i)
            af[i] = *(const half8*)&sa[(wm + i * 16 + lr) * 32 + k8];
#pragma unroll
        for (int j = 0; j < 4; ++j)
            bf[j] = *(const half8*)&sa[4096 + (wn + j * 16 + lr) * 32 + k8];
#pragma unroll
        for (int i = 0; i < 4; ++i)
#pragma unroll
            for (int j = 0; j < 4; ++j)
                acc[i][j] = __builtin_amdgcn_mfma_f32_16x16x32_f16(
                    af[i], bf[j], acc[i][j], 0, 0, 0);
        ENDBAR();
        ++cur; if (cur >= 3) cur = 0;
    }

#pragma unroll
    for (int j = 0; j < 4; ++j) {
        const int col = n0 + wn + j * 16 + lr;
        const float bv = bias[col];
#pragma unroll
        for (int i = 0; i < 4; ++i) {
            const int rbase = m0 + wm + i * 16 + (lane >> 4) * 4;
#pragma unroll
            for (int rr = 0; rr < 4; ++rr)
                Cout[(rbase + rr) * 512 + col] = acc[i][j][rr] + bv;
        }
    }
}

// ---------------------------------------------------------------------------
// fold + normalize + GELU(tanh) + unfold, fused. One block per (bc, half):
// bc = bp*40+cch, half h covers tokens oh in [h*10, h*10+10).
// Stage oh-band [h*8, h*8+12) of h_t (49x432 f16, 42.3 KB) via global_load_lds,
// fold 34 image rows into ch (7.8 KB), unfold 360 tokens. Incremental index
// math throughout. 512 threads, 50 KB LDS -> 3 blocks/CU.
// ---------------------------------------------------------------------------
__global__ __launch_bounds__(512) void fold_unfold(
    const f16* __restrict__ h_t, f16* __restrict__ g16)
{
    __shared__ f16 stg[21168];         // [n=ki*7+kj][12 oh-rows * 36 ow]
    __shared__ f16 ch[3876];           // 34 rows x 114 cols
    const int bx = blockIdx.x;         // 0..1279
    const int bc = bx >> 1, h = bx & 1;
    const int bp = bc / 40, cch = bc % 40;
    const int tid = threadIdx.x;
    const int ohlo = h * 8;            // staged band [ohlo, ohlo+12)
    const int rowbase = h * 30;        // image rows [rowbase, rowbase+34)

    // ---- stage band: 2646 16B segments, LDS-contiguous ----
    {
        const f16* src0 = h_t + cch * 49 * 11520 + bp * 720 + ohlo * 36;
        for (int s = tid; s < 2646; s += 512) {
            const int n = s / 54, i = s - n * 54;
            load16_lds(src0 + n * 11520 + i * 8, &stg[s * 8]);
        }
    }
    WAIT0_BARRIER();

    // ---- fold + normalize + GELU: column fixed per thread ----
    {
        const int c  = tid & 127;          // column (active < 114)
        const int rl = tid >> 7;           // row slot 0..3
        // per-thread column taps (computed once)
        int kjs[3], ows[3], nc = 0;
        int qc = 0, cm = 0;
        if (c < 114) {
            qc = c / 3; cm = c - 3 * qc;
#pragma unroll
            for (int t = 0; t < 3; ++t) {
                const int kj = cm + 3 * t, ow = qc - t;
                if (kj < 7 && ow >= 0 && ow < 36) { kjs[nc] = kj; ows[nc] = ow; ++nc; }
            }
        }
#pragma unroll
        for (int p = 0; p < 9; ++p) {
            const int rloc = rl + 4 * p;
            if (rloc >= 34) break;
            const int r = rowbase + rloc;
            float outv = 0.f;
            if (c >= 3 && c < 111 && r >= 3 && r < 63) {
                const int qr = r / 3, rm = r % 3;
                float sum = 0.f;
                int cnt = 0;
#pragma unroll
                for (int t = 0; t < 3; ++t) {
                    const int ki = rm + 3 * t, oh = qr - t;
                    if (ki < 7 && oh >= 0 && oh < 20) {
                        const int rowoff = (oh - ohlo) * 36;
                        for (int b = 0; b < nc; ++b)
                            sum += (float)stg[(ki * 7 + kjs[b]) * 432 + rowoff + ows[b]];
                        cnt += nc;
                    }
                }
                const float xv = sum / (float)cnt;
                // tanh-approx GELU (max abs err ~3e-4), NaN-safe
                const float arg = xv * (0.7978845608028654f
                                        + 0.035677408136300125f * xv * xv);
                const float e = __expf(2.f * arg);
                outv = 0.5f * xv * (2.f - 2.f / (e + 1.f));
            }
            if (c < 114) ch[rloc * 114 + c] = (f16)outv;
        }
    }
    ENDBAR();

    // ---- unfold: k fixed per thread, incremental walk over l ----
    if (tid < 490) {
        const int k  = tid % 49;
        const int l0 = tid / 49;           // 0..9
        const int ki = k / 7, kj = k - ki * 7;
        int pix = ki * 114 + l0 * 3 + kj;  // local ch addr (rowbase-relative)
        int ow  = l0;                       // ow of current l
        f16* gdst = g16 + (bp * 720 + h * 360 + l0) * 2048 + cch * 49 + k;
#pragma unroll 4
        for (int step = 0; step < 36; ++step) {
            *gdst = ch[pix];
            gdst += 10 * 2048;
            ow += 10;
            // wrap: row +3 (+342), col delta 3*(ow+10-36-ow) = -78 -> net +264
            if (ow >= 36) { ow -= 36; pix += 264; }
            else          { pix += 30; }
        }
    }
    // zero tail cols [1960,2048) for this token half (4 of 40 cch blocks)
    if (cch >= 36) {
        const int cb = 1960 + (cch - 36) * 22;
        for (int flat = tid; flat < 360 * 22; flat += 512) {
            const int l = h * 360 + flat / 22, k = flat - (flat / 22) * 22;
            g16[(bp * 720 + l) * 2048 + cb + k] = (f16)0.f;
        }
    }
}

// ---------------------------------------------------------------------------
// prep: fuses x->f16 convert + both weight transposes (one dispatch).
// blocks [0,5760): cvt; [5760,6784): W1 -> W1t; [6784,7808): W2 -> W2t
// ---------------------------------------------------------------------------
__global__ __launch_bounds__(256) void prep(
    const float* __restrict__ x, f16* __restrict__ xh,
    const float* __restrict__ W1, f16* __restrict__ W1t,
    const float* __restrict__ W2, f16* __restrict__ W2t)
{
    __shared__ float tile[32][33];
    const int b = blockIdx.x, t = threadIdx.x;
    if (b < 5760) {
        const int i = b * 256 + t;     // < 1474560 float4s
        const float4 v = ((const float4*)x)[i];
        half4 o;
        o[0] = (f16)v.x; o[1] = (f16)v.y; o[2] = (f16)v.z; o[3] = (f16)v.w;
        ((half4*)xh)[i] = o;
        return;
    }
    const float* src; f16* dst; int R, C, Rp, Cp, bx, by;
    if (b < 6784) {
        const int local = b - 5760;    // grid (16,64)
        bx = local & 15; by = local >> 4;
        src = W1; dst = W1t; R = 512; C = 1960; Rp = 512; Cp = 2048;
    } else {
        const int local = b - 6784;    // grid (64,16)
        bx = local & 63; by = local >> 6;
        src = W2; dst = W2t; R = 1960; C = 512; Rp = 2048; Cp = 512;
    }
    const int r0 = bx * 32, c0 = by * 32;
    const int tx = t & 31, ty = t >> 5;
#pragma unroll
    for (int i = 0; i < 32; i += 8) {
        const int r = r0 + ty + i, c = c0 + tx;
        tile[ty + i][tx] = (r < R && c < C) ? src[r * C + c] : 0.f;
    }
    __syncthreads();
#pragma unroll
    for (int i = 0; i < 32; i += 8) {
        const int c = c0 + ty + i, r = r0 + tx;
        if (c < Cp && r < Rp) dst[c * Rp + r] = (f16)tile[tx][ty + i];
    }
}

// ---------------------------------------------------------------------------
extern "C" void kernel_launch(void* const* d_in, const int* in_sizes, int n_in,
                              void* d_out, int out_size, void* d_ws, size_t ws_size,
                              hipStream_t stream)
{
    const float* x  = (const float*)d_in[0];
    const float* W1 = (const float*)d_in[1];
    const float* b1 = (const float*)d_in[2];
    const float* W2 = (const float*)d_in[3];
    const float* b2 = (const float*)d_in[4];

    char* ws = (char*)d_ws;
    f16* xh   = (f16*)(ws);                                       // 11,796,480 B
    f16* W1t  = (f16*)(ws + 11796480);                            //  2,097,152 B
    f16* W2t  = (f16*)(ws + 11796480 + 2097152);                  //  2,097,152 B
    f16* h_t  = (f16*)(ws + 11796480 + 2 * 2097152);              // 47,185,920 B
    f16* g16  = (f16*)(ws + 11796480 + 2 * 2097152 + 47185920);   // 47,185,920 B

    // fused convert + transposes
    prep<<<dim3(7808), dim3(256), 0, stream>>>(x, xh, W1, W1t, W2, W2t);
    // GEMM1 (3-stage pipelined): h_t = W1t @ xh^T + b1(row)
    gemm1<<<dim3(1536), dim3(256), 0, stream>>>(W1t, xh, b1, h_t);
    // fused fold + normalize + GELU + unfold (banded LDS, incremental index)
    fold_unfold<<<dim3(1280), dim3(512), 0, stream>>>(h_t, g16);
    // GEMM2 (3-stage pipeline, XCD-swizzled): out = g16 @ W2t^T + b2
    gemm2<<<dim3(384), dim3(256), 0, stream>>>(g16, W2t, b2, (float*)d_out);
}